// Round 4
// baseline (4399.923 us; speedup 1.0000x reference)
//
#include <hip/hip_runtime.h>
#include <hip/hip_bf16.h>
#include <math.h>

typedef __attribute__((ext_vector_type(8))) short short8;
typedef __attribute__((ext_vector_type(4))) float f32x4;

// B=4096, S=64, V=50000, D=300, H=6, E=400, VS=200, DH=50

// ws layout (ushort elems): MFMA B-frag tiles, 512 elems each:
// elem(lane,i) = W[k][n], n = tn*16+(lane&15), k = kt*32+(lane>>4)*8+i
#define QF 0        // [20 tn][10 kt][512]  Wq + aug cols n=300..305 (cq_h)
#define KF 102400   // [19][10][512]  Wk
#define VF 199680   // [19][10][512]  Wv
#define OF 296960   // [19][10][512]  Wo
#define RF 394240   // [19][10][512]  Wro = Wr @ Wo (per-head block product)
#define PFW 491520  // [25][10][512]  Wp
#define AFW 619520  // [13][13][512]  Wa
#define BOBF 706048 // float[304] at byte 2*BOBF: fused attn bias bo + br@Wo
#define PREP_TOTAL (706048 + 304)

__device__ __forceinline__ unsigned short f2b(float f) {
  unsigned int u = __builtin_bit_cast(unsigned int, f);
  u += 0x7FFFu + ((u >> 16) & 1u);
  return (unsigned short)(u >> 16);
}
__device__ __forceinline__ float b2f(unsigned short h) {
  unsigned int u = ((unsigned int)h) << 16;
  return __builtin_bit_cast(float, u);
}

__global__ void prep_weights(const float* __restrict__ Wq, const float* __restrict__ Wk,
                             const float* __restrict__ Wv, const float* __restrict__ Wr,
                             const float* __restrict__ Wo, const float* __restrict__ Wp,
                             const float* __restrict__ Wa, const float* __restrict__ wq_attn,
                             const float* __restrict__ br, const float* __restrict__ bo,
                             unsigned short* __restrict__ ws) {
  int idx = blockIdx.x * blockDim.x + threadIdx.x;
  if (idx >= PREP_TOTAL) return;
  if (idx >= BOBF) {                      // fused attn-out bias (fp32)
    int n = idx - BOBF;                   // 0..303
    float s = 0.f;
    if (n < 300) {
      s = bo[n];
      for (int m = 0; m < 300; ++m) s += br[m % 50] * Wo[m * 300 + n];
    }
    ((float*)(ws))[BOBF / 2 + n] = s;
    return;
  }
  float val = 0.f;
  if (idx < KF) {                         // Q' = [Wq | cq_h]
    int tn = idx / 5120, r = idx % 5120;
    int kt = r / 512; r &= 511;
    int lane = r >> 3, i = r & 7;
    int n = tn * 16 + (lane & 15), k = kt * 32 + (lane >> 4) * 8 + i;
    if (k < 300) {
      if (n < 300) val = Wq[k * 300 + n];
      else if (n < 306) {
        int h = n - 300;
        float s = 0.f;
        for (int d = 0; d < 50; ++d) s += Wq[k * 300 + 50 * h + d] * wq_attn[h * 50 + d];
        val = s;
      }
    }
  } else if (idx < RF) {                  // Wk / Wv / Wo (plain 300x300)
    int m = (idx - KF) / 97280;
    int local = (idx - KF) % 97280;
    int tn = local / 5120, r = local % 5120;
    int kt = r / 512; r &= 511;
    int lane = r >> 3, i = r & 7;
    int n = tn * 16 + (lane & 15), k = kt * 32 + (lane >> 4) * 8 + i;
    if (n < 300 && k < 300) {
      const float* W = (m == 0) ? Wk : (m == 1) ? Wv : Wo;
      val = W[k * 300 + n];
    }
  } else if (idx < PFW) {                 // Wro[k][n] = sum_j Wr[k%50][j]*Wo[50*(k/50)+j][n]
    int local = idx - RF;
    int tn = local / 5120, r = local % 5120;
    int kt = r / 512; r &= 511;
    int lane = r >> 3, i = r & 7;
    int n = tn * 16 + (lane & 15), k = kt * 32 + (lane >> 4) * 8 + i;
    if (n < 300 && k < 300) {
      int h = k / 50, i2 = k % 50;
      float s = 0.f;
      for (int j = 0; j < 50; ++j) s += Wr[i2 * 50 + j] * Wo[(50 * h + j) * 300 + n];
      val = s;
    }
  } else if (idx < AFW) {                 // Wp [300][400]
    int local = idx - PFW;
    int tn = local / 5120, r = local % 5120;
    int kt = r / 512; r &= 511;
    int lane = r >> 3, i = r & 7;
    int n = tn * 16 + (lane & 15), k = kt * 32 + (lane >> 4) * 8 + i;
    if (k < 300) val = Wp[k * 400 + n];
  } else {                                // Wa [400][200], 13 kt
    int local = idx - AFW;
    int tn = local / 6656, r = local % 6656;
    int kt = r / 512; r &= 511;
    int lane = r >> 3, i = r & 7;
    int n = tn * 16 + (lane & 15), k = kt * 32 + (lane >> 4) * 8 + i;
    if (n < 200 && k < 400) val = Wa[k * 200 + n];
  }
  ws[idx] = f2b(val);
}

// LDS layout (bytes). misc FIRST so fragment over-reads never hit fp32 bits.
#define MISC_OFF 0      // float[1280]: aM[384] gkf[320] scp[512] wsm[64]
#define KB_OFF 5120     // ushort [64][344]  K (head-padded cols 56h+d) -> attn_out
#define QB_OFF 49152    // ushort [64][312]  q
#define VB_OFF 89088    // ushort [64][312]  v
#define HB_OFF 49152    // ushort [64][408]  h (overlays qb+vb after attn)
#define SMEM_BYTES 125088  // includes 64B tail pad for guarded over-reads

#define KSTR 344
#define QSTR 312
#define VSTR 312
#define HSTR 408

template <int KT>
__device__ __forceinline__ void loadBT(short8* b, const unsigned short* p) {
#pragma unroll
  for (int kt = 0; kt < KT; ++kt) b[kt] = *(const short8*)(p + kt * 512);
}

template <int KT>
__device__ __forceinline__ void chain2(const short8* a0, const short8* a1, const short8* bf,
                                       f32x4& c0, f32x4& c1) {
  c0 = {0.f, 0.f, 0.f, 0.f};
  c1 = {0.f, 0.f, 0.f, 0.f};
#pragma unroll
  for (int k = 0; k < KT; ++k) {
    c0 = __builtin_amdgcn_mfma_f32_16x16x32_bf16(a0[k], bf[k], c0, 0, 0, 0);
    c1 = __builtin_amdgcn_mfma_f32_16x16x32_bf16(a1[k], bf[k], c1, 0, 0, 0);
  }
}

// 2 M-tiles per wave, STEP-way N split, 2-deep B prefetch.
template <int KT, typename Epi>
__device__ __forceinline__ void gemm2(const unsigned short* wbase, const short8* a0,
                                      const short8* a1, int t0, int step, int nt, int lane,
                                      Epi epi) {
  short8 b0[KT], b1[KT];
  int t = t0;
  if (t >= nt) return;
  loadBT<KT>(b0, wbase + (size_t)t * (KT * 512) + lane * 8);
  f32x4 c0, c1;
  while (true) {
    if (t + step < nt) loadBT<KT>(b1, wbase + (size_t)(t + step) * (KT * 512) + lane * 8);
    chain2<KT>(a0, a1, b0, c0, c1);
    epi(t, c0, c1);
    t += step; if (t >= nt) break;
    if (t + step < nt) loadBT<KT>(b0, wbase + (size_t)(t + step) * (KT * 512) + lane * 8);
    chain2<KT>(a0, a1, b1, c0, c1);
    epi(t, c0, c1);
    t += step; if (t >= nt) break;
  }
}

__global__ __launch_bounds__(1024) void doc_encoder(
    const int* __restrict__ tokens, const float* __restrict__ emb,
    const float* __restrict__ wk_attn, const float* __restrict__ bp_,
    const float* __restrict__ ba_, const float* __restrict__ va_,
    const unsigned short* __restrict__ ws, float* __restrict__ out) {
  __shared__ alignas(16) unsigned char smem[SMEM_BYTES];
  float* miscf = (float*)(smem + MISC_OFF);
  unsigned short* kb = (unsigned short*)(smem + KB_OFF);
  unsigned short* qb = (unsigned short*)(smem + QB_OFF);
  unsigned short* vb = (unsigned short*)(smem + VB_OFF);
  unsigned short* hb = (unsigned short*)(smem + HB_OFF);
  float* gkf = miscf + 384;   // [320]
  float* scp = miscf + 704;   // [8][64]
  float* wsm = miscf + 1216;  // [64]

  const int b = blockIdx.x;
  const int tid = threadIdx.x;
  const int lane = tid & 63;
  const int wv = tid >> 6;       // 0..15
  const int wm2 = wv & 1;        // M half (rows wm2*32 .. +32)
  const int w8 = wv >> 1;        // 8-way N split
  const int l15 = lane & 15;
  const int lg = lane >> 4;
  const int kofs = lg * 8;
  const int arow0 = wm2 * 32 + l15;
  const int arow1 = arow0 + 16;
  const int cr0 = wm2 * 32 + lg * 4;   // C rows tile0; tile1 = +16
  const float* bobf = (const float*)(ws + BOBF);

  // ---- zero qb pad cols 300..311 (block-start LDS may hold NaN bit patterns) ----
  for (int i = tid; i < 64 * 12; i += 1024) qb[(i / 12) * QSTR + 300 + (i % 12)] = 0;
  if (tid < 20) gkf[300 + tid] = 0.f;

  // ---- gather x rows straight into A-fragments (registers) ----
  short8 ax0[10], ax1[10];
  {
    int tok0 = tokens[b * 64 + arow0];
    int tok1 = tokens[b * 64 + arow1];
    const float* rp0 = emb + (size_t)tok0 * 300;
    const float* rp1 = emb + (size_t)tok1 * 300;
#pragma unroll
    for (int kt = 0; kt < 9; ++kt) {
      f32x4 u0 = *(const f32x4*)(rp0 + kt * 32 + kofs);
      f32x4 u1 = *(const f32x4*)(rp0 + kt * 32 + kofs + 4);
      f32x4 v0 = *(const f32x4*)(rp1 + kt * 32 + kofs);
      f32x4 v1 = *(const f32x4*)(rp1 + kt * 32 + kofs + 4);
      short8 t0, t1;
#pragma unroll
      for (int j = 0; j < 4; ++j) {
        t0[j] = (short)f2b(u0[j]); t0[4 + j] = (short)f2b(u1[j]);
        t1[j] = (short)f2b(v0[j]); t1[4 + j] = (short)f2b(v1[j]);
      }
      ax0[kt] = t0; ax1[kt] = t1;
    }
    short8 t0, t1;
#pragma unroll
    for (int j = 0; j < 8; ++j) {
      int c = 288 + kofs + j;
      t0[j] = (c < 300) ? (short)f2b(rp0[c]) : (short)0;
      t1[j] = (c < 300) ? (short)f2b(rp1[c]) : (short)0;
    }
    ax0[9] = t0; ax1[9] = t1;
  }

  const float scale = 0.1414213562373095f;  // 50^-0.5

  // ---- Phase B: Q'(20) K(19) V(19) = 58 tile-jobs, stride w8 ----
  {
    auto jobPtr = [&](int j) -> const unsigned short* {
      size_t off;
      if (j < 20) off = QF + (size_t)j * 5120;
      else if (j < 39) off = KF + (size_t)(j - 20) * 5120;
      else off = VF + (size_t)(j - 39) * 5120;
      return ws + off + lane * 8;
    };
    auto bEpi = [&](int j, f32x4 c0, f32x4 c1) {
      if (j < 20) {
        int n = j * 16 + l15;
        if (n < 300) {
#pragma unroll
          for (int r = 0; r < 4; ++r) {
            qb[(cr0 + r) * QSTR + n] = f2b(c0[r]);
            qb[(cr0 + 16 + r) * QSTR + n] = f2b(c1[r]);
          }
        } else if (n < 306) {
          float* aMh = miscf + (n - 300) * 64;
#pragma unroll
          for (int r = 0; r < 4; ++r) {
            aMh[cr0 + r] = c0[r] * scale;
            aMh[cr0 + 16 + r] = c1[r] * scale;
          }
        }
      } else if (j < 39) {
        int n = (j - 20) * 16 + l15;
        if (n < 300) {
          int col = (n / 50) * 56 + (n % 50);   // head-padded K columns
#pragma unroll
          for (int r = 0; r < 4; ++r) {
            kb[(cr0 + r) * KSTR + col] = f2b(c0[r]);
            kb[(cr0 + 16 + r) * KSTR + col] = f2b(c1[r]);
          }
        }
      } else {
        int n = (j - 39) * 16 + l15;
        if (n < 300) {
#pragma unroll
          for (int r = 0; r < 4; ++r) {
            vb[(cr0 + r) * VSTR + n] = f2b(c0[r]);
            vb[(cr0 + 16 + r) * VSTR + n] = f2b(c1[r]);
          }
        }
      }
    };
    short8 wb0[10], wb1[10];
    f32x4 c0, c1;
    int j = w8;
    loadBT<10>(wb0, jobPtr(j));
    while (true) {
      if (j + 8 < 58) loadBT<10>(wb1, jobPtr(j + 8));
      chain2<10>(ax0, ax1, wb0, c0, c1);
      bEpi(j, c0, c1);
      j += 8; if (j >= 58) break;
      if (j + 8 < 58) loadBT<10>(wb0, jobPtr(j + 8));
      chain2<10>(ax0, ax1, wb1, c0, c1);
      bEpi(j, c0, c1);
      j += 8; if (j >= 58) break;
    }
  }
  __syncthreads();   // B1

  // ---- Stage C: wave h handles head h entirely in-wave ----
  if (wv < 6) {
    const int h = wv;
    float* aMh = miscf + h * 64;
    // alpha = softmax(logits)
    float lgt = aMh[lane];
    float m = lgt;
#pragma unroll
    for (int off = 32; off; off >>= 1) m = fmaxf(m, __shfl_xor(m, off));
    float e = __expf(lgt - m);
    float ss = e;
#pragma unroll
    for (int off = 32; off; off >>= 1) ss += __shfl_xor(ss, off);
    float alpha = e / ss;
    aMh[lane] = alpha;
    // g[d] = sum_s alpha[s] q[s,d]
    float g = 0.f;
    if (lane < 50) {
      const unsigned short* qcol = qb + 50 * h + lane;
      for (int s = 0; s < 64; ++s) g += aMh[s] * b2f(qcol[s * QSTR]);
    }
    float gw = (lane < 50) ? g * wk_attn[h * 50 + lane] : 0.f;
    aMh[lane] = gw;
    // beta logits p[s] = sum_d gw[d] k[s,d]  (head-contiguous K row slice)
    float p = 0.f;
    {
      const unsigned short* krow = kb + lane * KSTR + 56 * h;
      for (int d = 0; d < 50; ++d) p += aMh[d] * b2f(krow[d]);
    }
    p *= scale;
    m = p;
#pragma unroll
    for (int off = 32; off; off >>= 1) m = fmaxf(m, __shfl_xor(m, off));
    e = __expf(p - m);
    ss = e;
#pragma unroll
    for (int off = 32; off; off >>= 1) ss += __shfl_xor(ss, off);
    aMh[lane] = e / ss;   // beta
    // gk[d] = g[d] * sum_s beta[s] k[s,d]
    if (lane < 50) {
      float gks = 0.f;
      const unsigned short* kcol = kb + 56 * h + lane;
      for (int s = 0; s < 64; ++s) gks += aMh[s] * b2f(kcol[s * KSTR]);
      gkf[50 * h + lane] = g * gks;
    }
  }
  __syncthreads();   // B2

  // ---- attn_out = q@Wo + (gk o v)@Wro + bob -> kb (plain cols) ----
  {
    short8 aq0[10], aq1[10];
#pragma unroll
    for (int kt = 0; kt < 10; ++kt) {
      aq0[kt] = *(const short8*)&qb[arow0 * QSTR + kt * 32 + kofs];
      aq1[kt] = *(const short8*)&qb[arow1 * QSTR + kt * 32 + kofs];
    }
    gemm2<10>(ws + OF, aq0, aq1, w8, 8, 19, lane, [&](int t, f32x4 c0, f32x4 c1) {
      int n = t * 16 + l15;
      if (n < 300) {
        float bias = bobf[n];
#pragma unroll
        for (int r = 0; r < 4; ++r) {
          kb[(cr0 + r) * KSTR + n] = f2b(c0[r] + bias);
          kb[(cr0 + 16 + r) * KSTR + n] = f2b(c1[r] + bias);
        }
      }
    });
    // u fragments (gk o v), guarded at kt=9 against over-read garbage
    short8 au0[10], au1[10];
#pragma unroll
    for (int kt = 0; kt < 10; ++kt) {
      short8 vf0 = *(const short8*)&vb[arow0 * VSTR + kt * 32 + kofs];
      short8 vf1 = *(const short8*)&vb[arow1 * VSTR + kt * 32 + kofs];
      f32x4 g0 = *(const f32x4*)&gkf[kt * 32 + kofs];
      f32x4 g1 = *(const f32x4*)&gkf[kt * 32 + kofs + 4];
      short8 u0, u1;
#pragma unroll
      for (int j = 0; j < 8; ++j) {
        float gv = (j < 4) ? g0[j] : g1[j - 4];
        if (kt == 9 && (288 + kofs + j) >= 300) { u0[j] = 0; u1[j] = 0; }
        else {
          u0[j] = (short)f2b(gv * b2f((unsigned short)vf0[j]));
          u1[j] = (short)f2b(gv * b2f((unsigned short)vf1[j]));
        }
      }
      au0[kt] = u0; au1[kt] = u1;
    }
    gemm2<10>(ws + RF, au0, au1, w8, 8, 19, lane, [&](int t, f32x4 c0, f32x4 c1) {
      int n = t * 16 + l15;
      if (n < 300) {
#pragma unroll
        for (int r = 0; r < 4; ++r) {
          int i0 = (cr0 + r) * KSTR + n, i1 = (cr0 + 16 + r) * KSTR + n;
          kb[i0] = f2b(b2f(kb[i0]) + c0[r]);
          kb[i1] = f2b(b2f(kb[i1]) + c1[r]);
        }
      }
    });
  }
  __syncthreads();   // B3

  // ---- h = attn_out @ Wp + bp -> hb [64][408] (overlays qb+vb) ----
  {
    short8 ao0[10], ao1[10];
#pragma unroll
    for (int kt = 0; kt < 10; ++kt) {
      ao0[kt] = *(const short8*)&kb[arow0 * KSTR + kt * 32 + kofs];
      ao1[kt] = *(const short8*)&kb[arow1 * KSTR + kt * 32 + kofs];
    }
    gemm2<10>(ws + PFW, ao0, ao1, w8, 8, 25, lane, [&](int t, f32x4 c0, f32x4 c1) {
      int n = t * 16 + l15;   // < 400 always
      float bias = bp_[n];
#pragma unroll
      for (int r = 0; r < 4; ++r) {
        hb[(cr0 + r) * HSTR + n] = f2b(c0[r] + bias);
        hb[(cr0 + 16 + r) * HSTR + n] = f2b(c1[r] + bias);
      }
    });
  }
  __syncthreads();   // B4

  // ---- scores = tanh(h@Wa + ba) @ va ----
  {
    short8 ah0[13], ah1[13];
#pragma unroll
    for (int kt = 0; kt < 13; ++kt) {
      ah0[kt] = *(const short8*)&hb[arow0 * HSTR + kt * 32 + kofs];
      ah1[kt] = *(const short8*)&hb[arow1 * HSTR + kt * 32 + kofs];
    }
    float sp0[4] = {0.f, 0.f, 0.f, 0.f}, sp1[4] = {0.f, 0.f, 0.f, 0.f};
    gemm2<13>(ws + AFW, ah0, ah1, w8, 8, 13, lane, [&](int t, f32x4 c0, f32x4 c1) {
      int n = t * 16 + l15;
      if (n < 200) {
        float ban = ba_[n], van = va_[n];
#pragma unroll
        for (int r = 0; r < 4; ++r) {
          float x0 = fminf(fmaxf(c0[r] + ban, -15.f), 15.f);
          float x1 = fminf(fmaxf(c1[r] + ban, -15.f), 15.f);
          float t0 = __expf(2.f * x0), t1 = __expf(2.f * x1);
          sp0[r] += (t0 - 1.f) / (t0 + 1.f) * van;
          sp1[r] += (t1 - 1.f) / (t1 + 1.f) * van;
        }
      }
    });
#pragma unroll
    for (int off = 1; off < 16; off <<= 1) {
#pragma unroll
      for (int r = 0; r < 4; ++r) {
        sp0[r] += __shfl_xor(sp0[r], off);
        sp1[r] += __shfl_xor(sp1[r], off);
      }
    }
    if (l15 == 0) {
#pragma unroll
      for (int r = 0; r < 4; ++r) {
        scp[w8 * 64 + cr0 + r] = sp0[r];
        scp[w8 * 64 + cr0 + 16 + r] = sp1[r];
      }
    }
  }
  __syncthreads();   // B5
  if (wv == 0) {
    float x = 0.f;
#pragma unroll
    for (int w = 0; w < 8; ++w) x += scp[w * 64 + lane];
    float m = x;
#pragma unroll
    for (int off = 32; off; off >>= 1) m = fmaxf(m, __shfl_xor(m, off));
    float e = __expf(x - m);
    float ss = e;
#pragma unroll
    for (int off = 32; off; off >>= 1) ss += __shfl_xor(ss, off);
    wsm[lane] = e / ss;
  }
  __syncthreads();   // B6

  // ---- pooled[e] = sum_s wsm[s] h[s][e] ----
  if (tid < 400) {
    float a0 = 0.f, a1 = 0.f, a2 = 0.f, a3 = 0.f;
    for (int s = 0; s < 64; s += 4) {
      a0 += wsm[s] * b2f(hb[s * HSTR + tid]);
      a1 += wsm[s + 1] * b2f(hb[(s + 1) * HSTR + tid]);
      a2 += wsm[s + 2] * b2f(hb[(s + 2) * HSTR + tid]);
      a3 += wsm[s + 3] * b2f(hb[(s + 3) * HSTR + tid]);
    }
    out[(size_t)b * 400 + tid] = (a0 + a1) + (a2 + a3);
  }
}

extern "C" void kernel_launch(void* const* d_in, const int* in_sizes, int n_in,
                              void* d_out, int out_size, void* d_ws, size_t ws_size,
                              hipStream_t stream) {
  (void)in_sizes; (void)n_in; (void)out_size; (void)ws_size;
  const int* tokens = (const int*)d_in[0];
  const float* emb = (const float*)d_in[1];
  const float* Wq = (const float*)d_in[2];
  const float* Wk = (const float*)d_in[3];
  const float* Wv = (const float*)d_in[4];
  const float* wq_attn = (const float*)d_in[5];
  const float* wk_attn = (const float*)d_in[6];
  const float* Wr = (const float*)d_in[7];
  const float* br = (const float*)d_in[8];
  const float* Wo = (const float*)d_in[9];
  const float* bo = (const float*)d_in[10];
  const float* Wp = (const float*)d_in[11];
  const float* bp = (const float*)d_in[12];
  const float* Wa = (const float*)d_in[13];
  const float* ba = (const float*)d_in[14];
  const float* va = (const float*)d_in[15];
  unsigned short* wsb = (unsigned short*)d_ws;
  float* out = (float*)d_out;

  prep_weights<<<(PREP_TOTAL + 255) / 256, 256, 0, stream>>>(Wq, Wk, Wv, Wr, Wo, Wp, Wa,
                                                             wq_attn, br, bo, wsb);
  doc_encoder<<<4096, 1024, 0, stream>>>(tokens, emb, wk_attn, bp, ba, va, wsb, out);
}

// Round 6
// 868.145 us; speedup vs baseline: 5.0682x; 5.0682x over previous
//
#include <hip/hip_runtime.h>
#include <hip/hip_bf16.h>
#include <math.h>

typedef __attribute__((ext_vector_type(8))) short short8;
typedef __attribute__((ext_vector_type(4))) float f32x4;

// B=4096, S=64, V=50000, D=300, H=6, E=400, VS=200, DH=50

// ws layout (ushort elems): MFMA B-frag tiles, 512 elems each:
// elem(lane,i) = W[k][n], n = tn*16+(lane&15), k = kt*32+(lane>>4)*8+i
#define QF 0        // [20 tn][10 kt][512]  Wq + aug cols n=300..305 (cq_h)
#define KF 102400   // [19][10][512]  Wk
#define VF 199680   // [19][10][512]  Wv
#define OFC 296960  // [19 tn][20 kt][512]  fused [Wo ; Wro] (kt<10: Wo, kt>=10: Wr@Wo)
#define PFW 491520  // [25][10][512]  Wp
#define AFW 619520  // [13][13][512]  Wa
#define BOBF 706048 // float[304] at elem BOBF (byte 2*BOBF): bias bo + br@Wo
#define PREP_TOTAL (706048 + 608)

__device__ __forceinline__ unsigned short f2b(float f) {
  unsigned int u = __builtin_bit_cast(unsigned int, f);
  u += 0x7FFFu + ((u >> 16) & 1u);
  return (unsigned short)(u >> 16);
}
__device__ __forceinline__ float b2f(unsigned short h) {
  unsigned int u = ((unsigned int)h) << 16;
  return __builtin_bit_cast(float, u);
}

__global__ void prep_weights(const float* __restrict__ Wq, const float* __restrict__ Wk,
                             const float* __restrict__ Wv, const float* __restrict__ Wr,
                             const float* __restrict__ Wo, const float* __restrict__ Wp,
                             const float* __restrict__ Wa, const float* __restrict__ wq_attn,
                             const float* __restrict__ br, const float* __restrict__ bo,
                             unsigned short* __restrict__ ws) {
  int idx = blockIdx.x * blockDim.x + threadIdx.x;
  if (idx >= PREP_TOTAL) return;
  if (idx >= BOBF) {                      // fused attn-out bias (fp32)
    int n = idx - BOBF;                   // 0..607
    if (n >= 304) return;
    float s = 0.f;
    if (n < 300) {
      s = bo[n];
      for (int m = 0; m < 300; ++m) s += br[m % 50] * Wo[m * 300 + n];
    }
    ((float*)(ws))[BOBF / 2 + n] = s;
    return;
  }
  float val = 0.f;
  if (idx < KF) {                         // Q' = [Wq | cq_h]
    int tn = idx / 5120, r = idx % 5120;
    int kt = r / 512; r &= 511;
    int lane = r >> 3, i = r & 7;
    int n = tn * 16 + (lane & 15), k = kt * 32 + (lane >> 4) * 8 + i;
    if (k < 300) {
      if (n < 300) val = Wq[k * 300 + n];
      else if (n < 306) {
        int h = n - 300;
        float s = 0.f;
        for (int d = 0; d < 50; ++d) s += Wq[k * 300 + 50 * h + d] * wq_attn[h * 50 + d];
        val = s;
      }
    }
  } else if (idx < OFC) {                 // Wk / Wv (plain 300x300)
    int m = (idx - KF) / 97280;
    int local = (idx - KF) % 97280;
    int tn = local / 5120, r = local % 5120;
    int kt = r / 512; r &= 511;
    int lane = r >> 3, i = r & 7;
    int n = tn * 16 + (lane & 15), k = kt * 32 + (lane >> 4) * 8 + i;
    if (n < 300 && k < 300) {
      const float* W = (m == 0) ? Wk : Wv;
      val = W[k * 300 + n];
    }
  } else if (idx < PFW) {                 // fused [Wo ; Wro], 20 kt
    int local = idx - OFC;
    int tn = local / 10240, r = local % 10240;
    int kt = r / 512; r &= 511;
    int lane = r >> 3, i = r & 7;
    int n = tn * 16 + (lane & 15), kk = (lane >> 4) * 8 + i;
    if (n < 300) {
      if (kt < 10) {
        int k = kt * 32 + kk;
        if (k < 300) val = Wo[k * 300 + n];
      } else {
        int k = (kt - 10) * 32 + kk;
        if (k < 300) {                    // Wro[k][n] = sum_j Wr[k%50][j] Wo[50*(k/50)+j][n]
          int h = k / 50, i2 = k % 50;
          float s = 0.f;
          for (int j = 0; j < 50; ++j) s += Wr[i2 * 50 + j] * Wo[(50 * h + j) * 300 + n];
          val = s;
        }
      }
    }
  } else if (idx < AFW) {                 // Wp [300][400]
    int local = idx - PFW;
    int tn = local / 5120, r = local % 5120;
    int kt = r / 512; r &= 511;
    int lane = r >> 3, i = r & 7;
    int n = tn * 16 + (lane & 15), k = kt * 32 + (lane >> 4) * 8 + i;
    if (k < 300) val = Wp[k * 400 + n];
  } else {                                // Wa [400][200], 13 kt
    int local = idx - AFW;
    int tn = local / 6656, r = local % 6656;
    int kt = r / 512; r &= 511;
    int lane = r >> 3, i = r & 7;
    int n = tn * 16 + (lane & 15), k = kt * 32 + (lane >> 4) * 8 + i;
    if (n < 200 && k < 400) val = Wa[k * 200 + n];
  }
  ws[idx] = f2b(val);
}

// LDS layout (bytes), total 162624 <= 163840
#define MISC_OFF 0      // float[704]: aM[6][64] gkf[320]; overlay scp[8][64]+wsm[64]
#define XB 2816         // ushort [64][312]  x -> u
#define QB 42752        // ushort [64][312]  q   (hb overlays QB.. in phase E)
#define KB 82688        // ushort [64][312]  K
#define VB 122624       // ushort [64][312]  v -> attn_out
#define PAD_OFF 162560  // 64 B zeroed tail pad (vb row-63 kt=9 over-read target)
#define SMEM_BYTES 162624
#define STR 312
#define HSTR 408        // hb [64][408] at QB (52224 B, ends 94976 <= VB)

template <int KT>
__device__ __forceinline__ void loadBT(short8* b, const unsigned short* p) {
#pragma unroll
  for (int kt = 0; kt < KT; ++kt) b[kt] = *(const short8*)(p + kt * 512);
}

__global__ __launch_bounds__(1024, 4) void doc_encoder(
    const int* __restrict__ tokens, const float* __restrict__ emb,
    const float* __restrict__ wk_attn, const float* __restrict__ bp_,
    const float* __restrict__ ba_, const float* __restrict__ va_,
    const unsigned short* __restrict__ ws, float* __restrict__ out) {
  __shared__ alignas(16) unsigned char smem[SMEM_BYTES];
  float* miscf = (float*)(smem + MISC_OFF);
  unsigned short* xb = (unsigned short*)(smem + XB);
  unsigned short* qb = (unsigned short*)(smem + QB);
  unsigned short* kb = (unsigned short*)(smem + KB);
  unsigned short* vb = (unsigned short*)(smem + VB);
  unsigned short* hb = (unsigned short*)(smem + QB);   // overlay
  unsigned short* pad = (unsigned short*)(smem + PAD_OFF);
  float* gkf = miscf + 384;   // [320]
  float* scp = miscf;         // [8][64] overlay aM (dead by phase F)
  float* wsm = miscf + 512;   // [64]

  const int b = blockIdx.x;
  const int tid = threadIdx.x;
  const int lane = tid & 63;
  const int wv = tid >> 6;       // 0..15
  const int wm2 = wv & 1;        // M half (rows wm2*32 .. +31)
  const int w8 = wv >> 1;        // 8-way N split
  const int l15 = lane & 15;
  const int lg = lane >> 4;
  const int kofs = lg * 8;
  const int arow0 = wm2 * 32 + l15;
  const int arow1 = arow0 + 16;
  const int cr0 = wm2 * 32 + lg * 4;
  const float* bobf = (const float*)(ws + BOBF);

  // ---- zero pads: qb/kb/vb cols 300..311, gkf tail, smem tail pad,
  //      qb row-0 head (xb row-63 kt=9 over-read target during phase B) ----
  for (int i = tid; i < 64 * 12; i += 1024) {
    int s = i / 12, c = 300 + i % 12;
    qb[s * STR + c] = 0; kb[s * STR + c] = 0; vb[s * STR + c] = 0;
  }
  if (tid < 20) gkf[300 + tid] = 0.f;
  if (tid < 32) pad[tid] = 0;
  if (tid < 8) qb[tid] = 0;

  // ---- gather x = emb[tokens[b]] -> bf16 xb [64][312] ----
  for (int i = tid; i < 64 * 39; i += 1024) {
    int s = i / 39, c8 = (i % 39) * 8;
    int tok = tokens[b * 64 + s];
    const float* rp = emb + (size_t)tok * 300;
    short8 v;
    if (c8 + 8 <= 300) {
      f32x4 u0 = *(const f32x4*)(rp + c8);
      f32x4 u1 = *(const f32x4*)(rp + c8 + 4);
#pragma unroll
      for (int j = 0; j < 4; ++j) { v[j] = (short)f2b(u0[j]); v[4 + j] = (short)f2b(u1[j]); }
    } else {
#pragma unroll
      for (int j = 0; j < 8; ++j) v[j] = (c8 + j < 300) ? (short)f2b(rp[c8 + j]) : (short)0;
    }
    *(short8*)&xb[s * STR + c8] = v;
  }
  __syncthreads();   // B0

  const float scale = 0.1414213562373095f;  // 50^-0.5

  // ---- Phase B: Q'(20) K(19) V(19) = 58 jobs, stride 8; a0 resident, a1 streamed ----
  {
    short8 ax[10];
#pragma unroll
    for (int kt = 0; kt < 10; ++kt)
      ax[kt] = *(const short8*)&xb[arow0 * STR + kt * 32 + kofs];
    const unsigned short* a1b = xb + arow1 * STR + kofs;

    for (int j = w8; j < 58; j += 8) {
      const unsigned short* wb;
      if (j < 20) wb = ws + QF + (size_t)j * 5120 + lane * 8;
      else if (j < 39) wb = ws + KF + (size_t)(j - 20) * 5120 + lane * 8;
      else wb = ws + VF + (size_t)(j - 39) * 5120 + lane * 8;
      short8 bt[10];
      loadBT<10>(bt, wb);
      f32x4 c0 = {0.f, 0.f, 0.f, 0.f}, c1 = c0;
#pragma unroll
      for (int k = 0; k < 10; ++k) {
        c0 = __builtin_amdgcn_mfma_f32_16x16x32_bf16(ax[k], bt[k], c0, 0, 0, 0);
        short8 a1 = *(const short8*)(a1b + k * 32);
        c1 = __builtin_amdgcn_mfma_f32_16x16x32_bf16(a1, bt[k], c1, 0, 0, 0);
      }
      if (j < 20) {
        int n = j * 16 + l15;
        if (n < 300) {
#pragma unroll
          for (int r = 0; r < 4; ++r) {
            qb[(cr0 + r) * STR + n] = f2b(c0[r]);
            qb[(cr0 + 16 + r) * STR + n] = f2b(c1[r]);
          }
        } else if (n < 306) {
          float* aMh = miscf + (n - 300) * 64;
#pragma unroll
          for (int r = 0; r < 4; ++r) {
            aMh[cr0 + r] = c0[r] * scale;
            aMh[cr0 + 16 + r] = c1[r] * scale;
          }
        }
      } else if (j < 39) {
        int n = (j - 20) * 16 + l15;
        if (n < 300) {
#pragma unroll
          for (int r = 0; r < 4; ++r) {
            kb[(cr0 + r) * STR + n] = f2b(c0[r]);
            kb[(cr0 + 16 + r) * STR + n] = f2b(c1[r]);
          }
        }
      } else {
        int n = (j - 39) * 16 + l15;
        if (n < 300) {
#pragma unroll
          for (int r = 0; r < 4; ++r) {
            vb[(cr0 + r) * STR + n] = f2b(c0[r]);
            vb[(cr0 + 16 + r) * STR + n] = f2b(c1[r]);
          }
        }
      }
    }
  }
  __syncthreads();   // B1

  // ---- Stage C: wave h handles head h entirely in-wave ----
  if (wv < 6) {
    const int h = wv;
    float* aMh = miscf + h * 64;
    float lgt = aMh[lane];
    float m = lgt;
#pragma unroll
    for (int off = 32; off; off >>= 1) m = fmaxf(m, __shfl_xor(m, off));
    float e = __expf(lgt - m);
    float ss = e;
#pragma unroll
    for (int off = 32; off; off >>= 1) ss += __shfl_xor(ss, off);
    aMh[lane] = e / ss;   // alpha
    float g = 0.f;
    if (lane < 50) {
      const unsigned short* qcol = qb + 50 * h + lane;
      for (int s = 0; s < 64; ++s) g += aMh[s] * b2f(qcol[s * STR]);
    }
    float gw = (lane < 50) ? g * wk_attn[h * 50 + lane] : 0.f;
    aMh[lane] = gw;
    float p = 0.f;
    {
      const unsigned short* krow = kb + lane * STR + 50 * h;
      for (int d = 0; d < 50; ++d) p += aMh[d] * b2f(krow[d]);
    }
    p *= scale;
    m = p;
#pragma unroll
    for (int off = 32; off; off >>= 1) m = fmaxf(m, __shfl_xor(m, off));
    e = __expf(p - m);
    ss = e;
#pragma unroll
    for (int off = 32; off; off >>= 1) ss += __shfl_xor(ss, off);
    aMh[lane] = e / ss;   // beta
    if (lane < 50) {
      float gks = 0.f;
      const unsigned short* kcol = kb + 50 * h + lane;
      for (int s = 0; s < 64; ++s) gks += aMh[s] * b2f(kcol[s * STR]);
      gkf[50 * h + lane] = g * gks;
    }
  }
  __syncthreads();   // B2

  // ---- u = gk o v -> xb (x dead), all cols 0..311 defined ----
  for (int i = tid; i < 64 * 39; i += 1024) {
    int s = i / 39, c8 = (i % 39) * 8;
    short8 vf = *(const short8*)&vb[s * STR + c8];
    short8 uf;
#pragma unroll
    for (int j = 0; j < 8; ++j) {
      int c = c8 + j;
      uf[j] = (c < 300) ? (short)f2b(gkf[c] * b2f((unsigned short)vf[j])) : (short)0;
    }
    *(short8*)&xb[s * STR + c8] = uf;
  }
  __syncthreads();   // B3

  // ---- attn_out = [q|u] @ [Wo;Wro] + bobf -> vb (19 jobs, 20 kt) ----
  {
    const unsigned short* aq0 = qb + arow0 * STR + kofs;
    const unsigned short* aq1 = qb + arow1 * STR + kofs;
    const unsigned short* au0 = xb + arow0 * STR + kofs;
    const unsigned short* au1 = xb + arow1 * STR + kofs;
    for (int t = w8; t < 19; t += 8) {
      short8 bt[20];
      loadBT<20>(bt, ws + OFC + (size_t)t * 10240 + lane * 8);
      f32x4 c0 = {0.f, 0.f, 0.f, 0.f}, c1 = c0;
#pragma unroll
      for (int k = 0; k < 10; ++k) {
        short8 a0 = *(const short8*)(aq0 + k * 32);
        c0 = __builtin_amdgcn_mfma_f32_16x16x32_bf16(a0, bt[k], c0, 0, 0, 0);
        short8 a1 = *(const short8*)(aq1 + k * 32);
        c1 = __builtin_amdgcn_mfma_f32_16x16x32_bf16(a1, bt[k], c1, 0, 0, 0);
      }
#pragma unroll
      for (int k = 0; k < 10; ++k) {
        short8 a0 = *(const short8*)(au0 + k * 32);
        c0 = __builtin_amdgcn_mfma_f32_16x16x32_bf16(a0, bt[10 + k], c0, 0, 0, 0);
        short8 a1 = *(const short8*)(au1 + k * 32);
        c1 = __builtin_amdgcn_mfma_f32_16x16x32_bf16(a1, bt[10 + k], c1, 0, 0, 0);
      }
      int n = t * 16 + l15;
      if (n < 300) {
        float bias = bobf[n];
#pragma unroll
        for (int r = 0; r < 4; ++r) {
          vb[(cr0 + r) * STR + n] = f2b(c0[r] + bias);
          vb[(cr0 + 16 + r) * STR + n] = f2b(c1[r] + bias);
        }
      }
    }
  }
  __syncthreads();   // B4

  // ---- h = attn_out @ Wp + bp -> hb [64][408] (overlays qb+kb) ----
  {
    short8 av[10];
#pragma unroll
    for (int kt = 0; kt < 10; ++kt)
      av[kt] = *(const short8*)&vb[arow0 * STR + kt * 32 + kofs];
    const unsigned short* a1b = vb + arow1 * STR + kofs;
    for (int t = w8; t < 25; t += 8) {
      short8 bt[10];
      loadBT<10>(bt, ws + PFW + (size_t)t * 5120 + lane * 8);
      f32x4 c0 = {0.f, 0.f, 0.f, 0.f}, c1 = c0;
#pragma unroll
      for (int k = 0; k < 10; ++k) {
        c0 = __builtin_amdgcn_mfma_f32_16x16x32_bf16(av[k], bt[k], c0, 0, 0, 0);
        short8 a1 = *(const short8*)(a1b + k * 32);
        c1 = __builtin_amdgcn_mfma_f32_16x16x32_bf16(a1, bt[k], c1, 0, 0, 0);
      }
      int n = t * 16 + l15;   // < 400
      float bias = bp_[n];
#pragma unroll
      for (int r = 0; r < 4; ++r) {
        hb[(cr0 + r) * HSTR + n] = f2b(c0[r] + bias);
        hb[(cr0 + 16 + r) * HSTR + n] = f2b(c1[r] + bias);
      }
    }
  }
  __syncthreads();   // B5

  // ---- scores = tanh(h@Wa + ba) @ va -> scp ----
  {
    const unsigned short* a0b = hb + arow0 * HSTR + kofs;
    const unsigned short* a1b = hb + arow1 * HSTR + kofs;
    float sp0[4] = {0.f, 0.f, 0.f, 0.f}, sp1[4] = {0.f, 0.f, 0.f, 0.f};
    for (int t = w8; t < 13; t += 8) {
      short8 bt[13];
      loadBT<13>(bt, ws + AFW + (size_t)t * 6656 + lane * 8);
      f32x4 c0 = {0.f, 0.f, 0.f, 0.f}, c1 = c0;
#pragma unroll
      for (int k = 0; k < 13; ++k) {
        short8 a0 = *(const short8*)(a0b + k * 32);
        c0 = __builtin_amdgcn_mfma_f32_16x16x32_bf16(a0, bt[k], c0, 0, 0, 0);
        short8 a1 = *(const short8*)(a1b + k * 32);
        c1 = __builtin_amdgcn_mfma_f32_16x16x32_bf16(a1, bt[k], c1, 0, 0, 0);
      }
      int n = t * 16 + l15;
      if (n < 200) {
        float ban = ba_[n], van = va_[n];
#pragma unroll
        for (int r = 0; r < 4; ++r) {
          float x0 = fminf(fmaxf(c0[r] + ban, -15.f), 15.f);
          float x1 = fminf(fmaxf(c1[r] + ban, -15.f), 15.f);
          float t0 = __expf(2.f * x0), t1 = __expf(2.f * x1);
          sp0[r] += (t0 - 1.f) / (t0 + 1.f) * van;
          sp1[r] += (t1 - 1.f) / (t1 + 1.f) * van;
        }
      }
    }
#pragma unroll
    for (int off = 1; off < 16; off <<= 1) {
#pragma unroll
      for (int r = 0; r < 4; ++r) {
        sp0[r] += __shfl_xor(sp0[r], off);
        sp1[r] += __shfl_xor(sp1[r], off);
      }
    }
    if (l15 == 0) {
#pragma unroll
      for (int r = 0; r < 4; ++r) {
        scp[w8 * 64 + cr0 + r] = sp0[r];
        scp[w8 * 64 + cr0 + 16 + r] = sp1[r];
      }
    }
  }
  __syncthreads();   // B6
  if (wv == 0) {
    float x = 0.f;
#pragma unroll
    for (int w = 0; w < 8; ++w) x += scp[w * 64 + lane];
    float m = x;
#pragma unroll
    for (int off = 32; off; off >>= 1) m = fmaxf(m, __shfl_xor(m, off));
    float e = __expf(x - m);
    float ss = e;
#pragma unroll
    for (int off = 32; off; off >>= 1) ss += __shfl_xor(ss, off);
    wsm[lane] = e / ss;
  }
  __syncthreads();   // B7

  // ---- pooled[e] = sum_s wsm[s] h[s][e] ----
  if (tid < 400) {
    float a0 = 0.f, a1 = 0.f, a2 = 0.f, a3 = 0.f;
    for (int s = 0; s < 64; s += 4) {
      a0 += wsm[s] * b2f(hb[s * HSTR + tid]);
      a1 += wsm[s + 1] * b2f(hb[(s + 1) * HSTR + tid]);
      a2 += wsm[s + 2] * b2f(hb[(s + 2) * HSTR + tid]);
      a3 += wsm[s + 3] * b2f(hb[(s + 3) * HSTR + tid]);
    }
    out[(size_t)b * 400 + tid] = (a0 + a1) + (a2 + a3);
  }
}

extern "C" void kernel_launch(void* const* d_in, const int* in_sizes, int n_in,
                              void* d_out, int out_size, void* d_ws, size_t ws_size,
                              hipStream_t stream) {
  (void)in_sizes; (void)n_in; (void)out_size; (void)ws_size;
  const int* tokens = (const int*)d_in[0];
  const float* emb = (const float*)d_in[1];
  const float* Wq = (const float*)d_in[2];
  const float* Wk = (const float*)d_in[3];
  const float* Wv = (const float*)d_in[4];
  const float* wq_attn = (const float*)d_in[5];
  const float* wk_attn = (const float*)d_in[6];
  const float* Wr = (const float*)d_in[7];
  const float* br = (const float*)d_in[8];
  const float* Wo = (const float*)d_in[9];
  const float* bo = (const float*)d_in[10];
  const float* Wp = (const float*)d_in[11];
  const float* bp = (const float*)d_in[12];
  const float* Wa = (const float*)d_in[13];
  const float* ba = (const float*)d_in[14];
  const float* va = (const float*)d_in[15];
  unsigned short* wsb = (unsigned short*)d_ws;
  float* out = (float*)d_out;

  prep_weights<<<(PREP_TOTAL + 255) / 256, 256, 0, stream>>>(Wq, Wk, Wv, Wr, Wo, Wp, Wa,
                                                             wq_attn, br, bo, wsb);
  doc_encoder<<<4096, 1024, 0, stream>>>(tokens, emb, wk_attn, bp, ba, va, wsb, out);
}